// Round 2
// baseline (461.170 us; speedup 1.0000x reference)
//
#include <hip/hip_runtime.h>

#define FEATSIZE 4096
#define TPB 256

// One block per row. Radix-select (MSB-first, 8 bits x 4 passes) over
// order-preserving u32 keys held entirely in registers (16/thread).
// LDS: 256-bin histogram + small scan scratch (~1.2 KB).
__global__ __launch_bounds__(TPB, 4) void adaptive_drop_kernel(
    const float* __restrict__ feat,
    const float* __restrict__ prop,
    const float* __restrict__ scale,
    float* __restrict__ out)
{
    __shared__ unsigned int hist[256];
    __shared__ unsigned int wtot[4];
    __shared__ unsigned int wsum[16];
    __shared__ unsigned int selB;
    __shared__ unsigned int selE;

    const int row  = blockIdx.x;
    const int t    = threadIdx.x;
    const int lane = t & 63;
    const int w    = t >> 6;

    const float p      = prop[row];
    const float rscale = scale[0] / p;
    int k = (int)rintf((float)FEATSIZE * p);   // matches jnp.round (half-to-even)
    k = k < 0 ? 0 : (k > FEATSIZE ? FEATSIZE : k);

    const float4* frow = reinterpret_cast<const float4*>(feat + (size_t)row * FEATSIZE);
    float4*       orow = reinterpret_cast<float4*>(out + (size_t)row * FEATSIZE);

    // ---- load + key transform (coalesced float4; keys stay in VGPRs) ----
    unsigned int keys[16];
#pragma unroll
    for (int j = 0; j < 4; ++j) {
        float4 v = frow[j * TPB + t];
        const float* vp = reinterpret_cast<const float*>(&v);
#pragma unroll
        for (int c = 0; c < 4; ++c) {
            unsigned int u = __float_as_uint(vp[c]);
            keys[j * 4 + c] = u ^ ((u & 0x80000000u) ? 0xFFFFFFFFu : 0x80000000u);
        }
    }

    // ---- trivial cases (uniform per block; not hit with setup's prop range) ----
    if (k <= 0 || k >= FEATSIZE) {
        const float m = (k >= FEATSIZE) ? rscale : 0.0f;
#pragma unroll
        for (int j = 0; j < 4; ++j) {
            float4 o; float* op = reinterpret_cast<float*>(&o);
#pragma unroll
            for (int c = 0; c < 4; ++c) {
                unsigned int key = keys[j * 4 + c];
                unsigned int u = (key & 0x80000000u) ? (key ^ 0x80000000u) : ~key;
                op[c] = __uint_as_float(u) * m;
            }
            orow[j * TPB + t] = o;
        }
        return;
    }

    // ---- radix select: find key T of rank k-1 (0-indexed ascending) ----
    int s = k - 1;
    unsigned int prefix = 0, maskHi = 0;
#pragma unroll
    for (int pass = 0; pass < 4; ++pass) {
        const int shift = 24 - 8 * pass;
        hist[t] = 0;
        __syncthreads();
#pragma unroll
        for (int e = 0; e < 16; ++e) {
            if (((keys[e] ^ prefix) & maskHi) == 0)
                atomicAdd(&hist[(keys[e] >> shift) & 255u], 1u);
        }
        __syncthreads();
        unsigned int val  = hist[t];
        unsigned int incl = val;
#pragma unroll
        for (int off = 1; off < 64; off <<= 1) {
            unsigned int o = __shfl_up(incl, (unsigned)off, 64);
            if (lane >= off) incl += o;
        }
        if (lane == 63) wtot[w] = incl;
        __syncthreads();
        unsigned int base = 0;
#pragma unroll
        for (int ww = 0; ww < 3; ++ww) if (ww < w) base += wtot[ww];
        const unsigned int cumIncl = base + incl;
        const unsigned int cumExcl = cumIncl - val;
        if (val != 0u && (int)cumExcl <= s && s < (int)cumIncl) {
            selB = (unsigned int)t;  // exactly one thread matches
            selE = cumExcl;
        }
        __syncthreads();
        prefix |= (selB << shift);
        s      -= (int)selE;
        maskHi |= (0xFFu << shift);
        // next pass's hist[t]=0 + barrier orders the selB/selE reuse safely
    }

    const unsigned int T = prefix;
    const int keepEq = s + 1;   // # of elements equal to T to keep (lowest index first)

    // ---- stable rank among elements equal to T, in global index order ----
    unsigned int laneExclJ[4];
#pragma unroll
    for (int j = 0; j < 4; ++j) {
        unsigned int cnt = 0;
#pragma unroll
        for (int c = 0; c < 4; ++c) {
            if (keys[j * 4 + c] == T) ++cnt;
        }
        unsigned int incl = cnt;
#pragma unroll
        for (int off = 1; off < 64; off <<= 1) {
            unsigned int o = __shfl_up(incl, (unsigned)off, 64);
            if (lane >= off) incl += o;
        }
        laneExclJ[j] = incl - cnt;
        if (lane == 63) wsum[j * 4 + w] = incl;   // per-(chunk j, wave w) totals
    }
    __syncthreads();
    unsigned int chunkExcl[4];
    {
        unsigned int run = 0;
#pragma unroll
        for (int m = 0; m < 16; ++m) {           // m = j*4 + w, global index order
            if ((m & 3) == w) chunkExcl[m >> 2] = run;
            run += wsum[m];
        }
    }

    // ---- masked, scaled write-out (coalesced float4) ----
#pragma unroll
    for (int j = 0; j < 4; ++j) {
        float4 o; float* op = reinterpret_cast<float*>(&o);
        const unsigned int base = chunkExcl[j] + laneExclJ[j];
        unsigned int eqseen = 0;
#pragma unroll
        for (int c = 0; c < 4; ++c) {
            const unsigned int key = keys[j * 4 + c];
            const unsigned int u = (key & 0x80000000u) ? (key ^ 0x80000000u) : ~key;
            const float f = __uint_as_float(u);
            bool keep;
            if (key < T)       keep = true;
            else if (key == T) { keep = ((int)(base + eqseen) < keepEq); ++eqseen; }
            else               keep = false;
            op[c] = keep ? f * rscale : 0.0f;
        }
        orow[j * TPB + t] = o;
    }
}

extern "C" void kernel_launch(void* const* d_in, const int* in_sizes, int n_in,
                              void* d_out, int out_size, void* d_ws, size_t ws_size,
                              hipStream_t stream) {
    const float* feat  = (const float*)d_in[0];
    const float* prop  = (const float*)d_in[1];
    const float* scale = (const float*)d_in[2];
    float* out = (float*)d_out;
    const int batch = in_sizes[1];   // prop has one entry per row
    adaptive_drop_kernel<<<batch, TPB, 0, stream>>>(feat, prop, scale, out);
}